// Round 8
// baseline (60.972 us; speedup 1.0000x reference)
//
#include <hip/hip_runtime.h>
#include <hip/hip_bf16.h>
#include <math.h>

// DistWeightLoss on MI355X — round 8: symmetric (upper-triangular) tiles.
// sim[i][j]==sim[j][i]: compute each 128x128 tile once (bj>=bi, 2080 blocks);
// off-diag tiles feed BOTH row-side (threshold thr[i]) and col-side
// (threshold thr[j]) accumulators. Diagonal tiles: row-side only + class
// check (they contain both orders). Halves MFMA/LDS/L2 vs round 7.
//
// ws layout: [0:N) pos_min f32 | [N:2N) row_sum f32 | [2N:3N) row_cnt f32
//            | [3N:) Xbf bf16 [N][D]

#define NN 8192
#define DD 128
#define KK 8
#define MARGIN 0.01f
#define NBI 64           // 8192/128 row-blocks

typedef __attribute__((ext_vector_type(8))) short short8;
typedef __attribute__((ext_vector_type(4))) float f32x4;

// ---------------- Threefry2x32 / JAX gumbel (bit-exact, validated) ----------------
__device__ __forceinline__ unsigned rotl32(unsigned x, unsigned r) {
    return (x << r) | (x >> (32u - r));
}

__device__ float gumbel_at(unsigned m) {
    const unsigned HALF = (NN * (KK - 1)) / 2;  // 28672
    unsigned c   = (m < HALF) ? m : (m - HALF);
    bool     hi  = (m >= HALF);
    const unsigned ks0 = 0u, ks1 = 42u;
    const unsigned ks2 = 0x1BD11BDAu ^ ks0 ^ ks1;
    unsigned x0 = c + ks0;
    unsigned x1 = (c + HALF) + ks1;
#define TF_ROUND(r) { x0 += x1; x1 = rotl32(x1, (r)); x1 ^= x0; }
    TF_ROUND(13) TF_ROUND(15) TF_ROUND(26) TF_ROUND(6)
    x0 += ks1; x1 += ks2 + 1u;
    TF_ROUND(17) TF_ROUND(29) TF_ROUND(16) TF_ROUND(24)
    x0 += ks2; x1 += ks0 + 2u;
    TF_ROUND(13) TF_ROUND(15) TF_ROUND(26) TF_ROUND(6)
    x0 += ks0; x1 += ks1 + 3u;
    TF_ROUND(17) TF_ROUND(29) TF_ROUND(16) TF_ROUND(24)
    x0 += ks1; x1 += ks2 + 4u;
    TF_ROUND(13) TF_ROUND(15) TF_ROUND(26) TF_ROUND(6)
    x0 += ks2; x1 += ks0 + 5u;
#undef TF_ROUND
    unsigned bits = hi ? x1 : x0;
    float f = __uint_as_float((bits >> 9) | 0x3f800000u) - 1.0f;
    float u = fmaxf(f, 1.17549435e-38f);
    return -logf(-logf(u));
}

// ---------------- fp32 -> bf16 (RNE) ----------------
__device__ __forceinline__ unsigned short bf16r(float f) {
    unsigned u = __float_as_uint(f);
    unsigned r = (u + 0x7FFFu + ((u >> 16) & 1u)) >> 16;
    return (unsigned short)r;
}

// ---------------- Kernel A: pos_min + cvt + zero-init ----------------
__global__ __launch_bounds__(64) void pos_kernel(const float* __restrict__ X,
                                                 float* __restrict__ pos_min,
                                                 float* __restrict__ row_sum,
                                                 float* __restrict__ row_cnt,
                                                 unsigned short* __restrict__ Xbf) {
    __shared__ float Xc[KK * DD];
    __shared__ float gram[KK * KK];
    const int c   = blockIdx.x;
    const int tid = threadIdx.x;

    if (tid < KK) {
        row_sum[c * KK + tid] = 0.f;
        row_cnt[c * KK + tid] = 0.f;
    }

    const float4* src = (const float4*)(X + (size_t)c * KK * DD);
    float4*       dst = (float4*)Xc;
#pragma unroll
    for (int it = 0; it < (KK * DD / 4) / 64; ++it)
        dst[tid + it * 64] = src[tid + it * 64];
    __syncthreads();

    ushort4* obf = (ushort4*)(Xbf + (size_t)c * KK * DD);
#pragma unroll
    for (int it = 0; it < 4; ++it) {
        int idx = tid + it * 64;
        float4 v = ((const float4*)Xc)[idx];
        ushort4 o;
        o.x = bf16r(v.x); o.y = bf16r(v.y); o.z = bf16r(v.z); o.w = bf16r(v.w);
        obf[idx] = o;
    }

    const int a = tid >> 3, b = tid & 7;
    float s = 0.f;
#pragma unroll
    for (int k = 0; k < DD; k += 4) {
        float4 va = *(const float4*)&Xc[a * DD + k];
        float4 vb = *(const float4*)&Xc[b * DD + k];
        s += va.x * vb.x + va.y * vb.y + va.z * vb.z + va.w * vb.w;
    }
    gram[a * KK + b] = s;
    __syncthreads();

    if (tid < KK) {
        const int r = tid;
        const int i = c * KK + r;
        float ps[KK - 1];
#pragma unroll
        for (int jj = 0; jj < KK - 1; ++jj)
            ps[jj] = gram[r * KK + ((r + 1 + jj) & (KK - 1))];
#pragma unroll
        for (int p = 0; p < KK - 2; ++p)
#pragma unroll
            for (int q = 0; q < KK - 2 - p; ++q) {
                float lo = fminf(ps[q], ps[q + 1]);
                float hi = fmaxf(ps[q], ps[q + 1]);
                ps[q] = lo; ps[q + 1] = hi;
            }
        float best = -1e30f;
        float pmin = ps[0];
#pragma unroll
        for (int jj = 0; jj < KK - 1; ++jj) {
            float g  = gumbel_at((unsigned)(i * (KK - 1) + jj));
            float sc = 5.0f * ps[jj] + g;
            if (sc > best) { best = sc; pmin = ps[jj]; }
        }
        pos_min[i] = pmin;
    }
}

// ---------------- async global->LDS 16B ----------------
__device__ __forceinline__ void async16(const void* g, void* l) {
    __builtin_amdgcn_global_load_lds(
        (const __attribute__((address_space(1))) unsigned int*)g,
        (__attribute__((address_space(3))) unsigned int*)l, 16, 0, 0);
}

// ---------------- Kernel B: symmetric 128x128 tile, dual-sided reduce ----------------
// B LDS rows = 128 bf16 = 256 B = 16 chunks of 16B. ds_read swizzle:
// byte ^= ((row&7)<<4); global_load_lds writes linearly so the SOURCE
// chunk index carries the same involution (rule #21).
__global__ __launch_bounds__(256, 2) void neg_sym_kernel(const unsigned short* __restrict__ Xbf,
                                                         const float* __restrict__ pos_min,
                                                         float* __restrict__ row_sum,
                                                         float* __restrict__ row_cnt) {
    __shared__ unsigned short Bs[128 * DD];  // 32 KB
    const int tid  = threadIdx.x;
    const int lane = tid & 63;
    const int w    = tid >> 6;      // 0..3 : 32-row band
    const int l15  = lane & 15, l4 = lane >> 4;

    // triangular decode: blockIdx.x -> (bi, bj), bj >= bi
    const int id = blockIdx.x;
    int bi = (int)(0.5f * (129.0f - sqrtf(16641.0f - 8.0f * (float)id)));
    if (bi < 0) bi = 0; if (bi > NBI - 1) bi = NBI - 1;
    while (bi * (129 - bi) / 2 > id) --bi;
    while ((bi + 1) * (128 - bi) / 2 <= id) ++bi;
    const int bj = bi + (id - bi * (129 - bi) / 2);
    const int i0 = bi * 128, j0 = bj * 128;
    const bool diag = (bi == bj);

    // ---- stage B panel (rows j0..j0+127): 2048 chunks, 8 per thread
#pragma unroll
    for (int it = 0; it < 8; ++it) {
        int ch  = it * 256 + tid;
        int row = ch >> 4, c4 = ch & 15, srcc = c4 ^ (row & 7);
        async16(Xbf + (((size_t)(j0 + row)) << 7) + srcc * 8, &Bs[ch * 8]);
    }

    // ---- A fragments -> registers (32 rows per wave)
    short8 areg[2][4];
#pragma unroll
    for (int m = 0; m < 2; ++m) {
        const int row = i0 + w * 32 + m * 16 + l15;
#pragma unroll
        for (int kk = 0; kk < 4; ++kk)
            areg[m][kk] = *(const short8*)(Xbf + (((size_t)row) << 7) + kk * 32 + l4 * 8);
    }

    // row-side thresholds / class ids (4-row quads lie within one 8-class)
    float thr[2][4];
    int   i3[2];
#pragma unroll
    for (int m = 0; m < 2; ++m) {
        const int ib = i0 + w * 32 + m * 16 + l4 * 4;
        i3[m] = ib >> 3;
#pragma unroll
        for (int r = 0; r < 4; ++r) thr[m][r] = pos_min[ib + r] - MARGIN;
    }
    // col-side thresholds (lane's 8 columns)
    float thrj[8];
#pragma unroll
    for (int n = 0; n < 8; ++n) thrj[n] = pos_min[j0 + n * 16 + l15] - MARGIN;

    __syncthreads();  // B resident (barrier drains vmcnt)

    // ---- compute: wave = 32 rows x 128 cols; acc[2][8]
    f32x4 acc[2][8] = {};
#pragma unroll
    for (int kk = 0; kk < 4; ++kk) {
        const int kb = (kk * 32 + l4 * 8) * 2;
#pragma unroll
        for (int n = 0; n < 8; ++n) {
            const int rb = n * 16 + l15;
            short8 b = *(const short8*)((const char*)Bs + ((rb * 256 + kb) ^ ((rb & 7) << 4)));
            acc[0][n] = __builtin_amdgcn_mfma_f32_16x16x32_bf16(areg[0][kk], b, acc[0][n], 0, 0, 0);
            acc[1][n] = __builtin_amdgcn_mfma_f32_16x16x32_bf16(areg[1][kk], b, acc[1][n], 0, 0, 0);
        }
    }

    // ---- epilogue (C/D layout: col=lane&15, row=(lane>>4)*4+reg)
    float s[2][4] = {{0.f}}, c[2][4] = {{0.f}};
    if (diag) {
        // row-side only (tile holds both orders), with class exclusion
#pragma unroll
        for (int n = 0; n < 8; ++n) {
            const int j3 = (j0 + n * 16 + l15) >> 3;
#pragma unroll
            for (int m = 0; m < 2; ++m)
#pragma unroll
                for (int r = 0; r < 4; ++r) {
                    float v = acc[m][n][r];
                    bool k = (v > thr[m][r]) && (i3[m] != j3);
                    s[m][r] += k ? v : 0.f;
                    c[m][r] += k ? 1.f : 0.f;
                }
        }
    } else {
        // dual-sided: row i (thr[i]) and col j (thr[j]); disjoint 128-blocks
        // never share a class -> no class check.
        float sc[8] = {0.f}, cc[8] = {0.f};
#pragma unroll
        for (int n = 0; n < 8; ++n) {
#pragma unroll
            for (int m = 0; m < 2; ++m)
#pragma unroll
                for (int r = 0; r < 4; ++r) {
                    float v = acc[m][n][r];
                    bool kr = (v > thr[m][r]);
                    s[m][r] += kr ? v : 0.f;
                    c[m][r] += kr ? 1.f : 0.f;
                    bool kc = (v > thrj[n]);
                    sc[n] += kc ? v : 0.f;
                    cc[n] += kc ? 1.f : 0.f;
                }
        }
        // col-side reduce: sum the 4 l4-quads (lanes l15, +16, +32, +48)
#pragma unroll
        for (int n = 0; n < 8; ++n) {
            float sv = sc[n], cv = cc[n];
            sv += __shfl_xor(sv, 16); cv += __shfl_xor(cv, 16);
            sv += __shfl_xor(sv, 32); cv += __shfl_xor(cv, 32);
            if (l4 == 0) {
                int j = j0 + n * 16 + l15;
                atomicAdd(&row_sum[j], sv);
                atomicAdd(&row_cnt[j], cv);
            }
        }
    }

    // row-side reduce across the 16 col-lanes, then atomics
#pragma unroll
    for (int m = 0; m < 2; ++m)
#pragma unroll
        for (int r = 0; r < 4; ++r) {
            float sv = s[m][r], cv = c[m][r];
#pragma unroll
            for (int off = 1; off < 16; off <<= 1) {
                sv += __shfl_xor(sv, off);
                cv += __shfl_xor(cv, off);
            }
            if (l15 == 0) {
                int i = i0 + w * 32 + m * 16 + l4 * 4 + r;
                atomicAdd(&row_sum[i], sv);
                atomicAdd(&row_cnt[i], cv);
            }
        }
}

// ---------------- Kernel C: finalize ----------------
__global__ __launch_bounds__(1024) void finalize_kernel(const float* __restrict__ row_sum,
                                                        const float* __restrict__ row_cnt,
                                                        const float* __restrict__ pos_min,
                                                        float* __restrict__ out) {
    __shared__ float red[1024];
    const int tid = threadIdx.x;
    float local = 0.f;
#pragma unroll
    for (int it = 0; it < NN / 1024; ++it) {
        int i = tid + it * 1024;
        float cnt = row_cnt[i];
        if (cnt > 0.f) {
            float nm = row_sum[i] / fmaxf(cnt, 1.0f);
            local += nm - pos_min[i] + MARGIN;
        }
    }
    red[tid] = local;
    __syncthreads();
    for (int st = 512; st > 0; st >>= 1) {
        if (tid < st) red[tid] += red[tid + st];
        __syncthreads();
    }
    if (tid == 0) out[0] = red[0] / (float)NN;
}

extern "C" void kernel_launch(void* const* d_in, const int* in_sizes, int n_in,
                              void* d_out, int out_size, void* d_ws, size_t ws_size,
                              hipStream_t stream) {
    const float* X = (const float*)d_in[0];
    float* pos_min = (float*)d_ws;
    float* row_sum = pos_min + NN;
    float* row_cnt = row_sum + NN;
    unsigned short* Xbf = (unsigned short*)((char*)d_ws + (size_t)3 * NN * 4);

    pos_kernel<<<NN / KK, 64, 0, stream>>>(X, pos_min, row_sum, row_cnt, Xbf);
    const int nblk = NBI * (NBI + 1) / 2;  // 2080
    neg_sym_kernel<<<nblk, 256, 0, stream>>>(Xbf, pos_min, row_sum, row_cnt);
    finalize_kernel<<<1, 1024, 0, stream>>>(row_sum, row_cnt, pos_min, (float*)d_out);
}

// Round 9
// 52.741 us; speedup vs baseline: 1.1561x; 1.1561x over previous
//
#include <hip/hip_runtime.h>
#include <hip/hip_bf16.h>
#include <math.h>

// DistWeightLoss on MI355X — round 9: 64-row A-panel in registers per wave
// (4x reuse of LDS B-reads), 128-col steps, bare launch bounds (no min-occ
// arg -> avoid r5/r8 spill regime). Symmetric variant reverted (r8: spilled).
//
// ws layout: [0:N) pos_min f32 | [N:2N) row_sum f32 | [2N:3N) row_cnt f32
//            | [3N:) Xbf bf16 [N][D]
//   A) pos_kernel: per-class 8x8 Gram (fp32, exact) + fused fp32->bf16 cvt
//      + zero-init of row_sum/row_cnt. Exact JAX Threefry gumbel -> pos_min.
//   B) neg_panel_kernel: grid 128x4 = 512 blocks (2/CU). 256 threads =
//      4 waves, ALL waves cover the same 64-row panel (areg[4][4] from
//      global, 64 VGPR); each wave owns a 32-col band of a 128-col step.
//      B: 128 rows/step double-buffered LDS (2x32... 2x(128x256B)=64 KB),
//      global_load_lds w/ pre-swizzled source. Per wave-step: 8 ds_read_b128
//      -> 32 MFMA. Register mask-accum; shfl-reduce + atomics once per block.
//   C) finalize_kernel: loss = sum(valid? s/c - pos + m : 0)/N.

#define NN 8192
#define DD 128
#define KK 8
#define MARGIN 0.01f

#define BM 64          // rows per block (= per wave, from registers)
#define BN 128         // cols per step (4 waves x 32)
#define JC 2048        // j-chunk per block
#define JT (JC / BN)   // 16 steps

typedef __attribute__((ext_vector_type(8))) short short8;
typedef __attribute__((ext_vector_type(4))) float f32x4;

// ---------------- Threefry2x32 / JAX gumbel (bit-exact, validated) ----------------
__device__ __forceinline__ unsigned rotl32(unsigned x, unsigned r) {
    return (x << r) | (x >> (32u - r));
}

__device__ float gumbel_at(unsigned m) {
    const unsigned HALF = (NN * (KK - 1)) / 2;  // 28672
    unsigned c   = (m < HALF) ? m : (m - HALF);
    bool     hi  = (m >= HALF);
    const unsigned ks0 = 0u, ks1 = 42u;
    const unsigned ks2 = 0x1BD11BDAu ^ ks0 ^ ks1;
    unsigned x0 = c + ks0;
    unsigned x1 = (c + HALF) + ks1;
#define TF_ROUND(r) { x0 += x1; x1 = rotl32(x1, (r)); x1 ^= x0; }
    TF_ROUND(13) TF_ROUND(15) TF_ROUND(26) TF_ROUND(6)
    x0 += ks1; x1 += ks2 + 1u;
    TF_ROUND(17) TF_ROUND(29) TF_ROUND(16) TF_ROUND(24)
    x0 += ks2; x1 += ks0 + 2u;
    TF_ROUND(13) TF_ROUND(15) TF_ROUND(26) TF_ROUND(6)
    x0 += ks0; x1 += ks1 + 3u;
    TF_ROUND(17) TF_ROUND(29) TF_ROUND(16) TF_ROUND(24)
    x0 += ks1; x1 += ks2 + 4u;
    TF_ROUND(13) TF_ROUND(15) TF_ROUND(26) TF_ROUND(6)
    x0 += ks2; x1 += ks0 + 5u;
#undef TF_ROUND
    unsigned bits = hi ? x1 : x0;
    float f = __uint_as_float((bits >> 9) | 0x3f800000u) - 1.0f;
    float u = fmaxf(f, 1.17549435e-38f);
    return -logf(-logf(u));
}

// ---------------- fp32 -> bf16 (RNE) ----------------
__device__ __forceinline__ unsigned short bf16r(float f) {
    unsigned u = __float_as_uint(f);
    unsigned r = (u + 0x7FFFu + ((u >> 16) & 1u)) >> 16;
    return (unsigned short)r;
}

// ---------------- Kernel A: pos_min + cvt + zero-init ----------------
__global__ __launch_bounds__(64) void pos_kernel(const float* __restrict__ X,
                                                 float* __restrict__ pos_min,
                                                 float* __restrict__ row_sum,
                                                 float* __restrict__ row_cnt,
                                                 unsigned short* __restrict__ Xbf) {
    __shared__ float Xc[KK * DD];
    __shared__ float gram[KK * KK];
    const int c   = blockIdx.x;
    const int tid = threadIdx.x;

    if (tid < KK) {
        row_sum[c * KK + tid] = 0.f;
        row_cnt[c * KK + tid] = 0.f;
    }

    const float4* src = (const float4*)(X + (size_t)c * KK * DD);
    float4*       dst = (float4*)Xc;
#pragma unroll
    for (int it = 0; it < (KK * DD / 4) / 64; ++it)
        dst[tid + it * 64] = src[tid + it * 64];
    __syncthreads();

    ushort4* obf = (ushort4*)(Xbf + (size_t)c * KK * DD);
#pragma unroll
    for (int it = 0; it < 4; ++it) {
        int idx = tid + it * 64;
        float4 v = ((const float4*)Xc)[idx];
        ushort4 o;
        o.x = bf16r(v.x); o.y = bf16r(v.y); o.z = bf16r(v.z); o.w = bf16r(v.w);
        obf[idx] = o;
    }

    const int a = tid >> 3, b = tid & 7;
    float s = 0.f;
#pragma unroll
    for (int k = 0; k < DD; k += 4) {
        float4 va = *(const float4*)&Xc[a * DD + k];
        float4 vb = *(const float4*)&Xc[b * DD + k];
        s += va.x * vb.x + va.y * vb.y + va.z * vb.z + va.w * vb.w;
    }
    gram[a * KK + b] = s;
    __syncthreads();

    if (tid < KK) {
        const int r = tid;
        const int i = c * KK + r;
        float ps[KK - 1];
#pragma unroll
        for (int jj = 0; jj < KK - 1; ++jj)
            ps[jj] = gram[r * KK + ((r + 1 + jj) & (KK - 1))];
#pragma unroll
        for (int p = 0; p < KK - 2; ++p)
#pragma unroll
            for (int q = 0; q < KK - 2 - p; ++q) {
                float lo = fminf(ps[q], ps[q + 1]);
                float hi = fmaxf(ps[q], ps[q + 1]);
                ps[q] = lo; ps[q + 1] = hi;
            }
        float best = -1e30f;
        float pmin = ps[0];
#pragma unroll
        for (int jj = 0; jj < KK - 1; ++jj) {
            float g  = gumbel_at((unsigned)(i * (KK - 1) + jj));
            float sc = 5.0f * ps[jj] + g;
            if (sc > best) { best = sc; pmin = ps[jj]; }
        }
        pos_min[i] = pmin;
    }
}

// ---------------- async global->LDS 16B ----------------
__device__ __forceinline__ void async16(const void* g, void* l) {
    __builtin_amdgcn_global_load_lds(
        (const __attribute__((address_space(1))) unsigned int*)g,
        (__attribute__((address_space(3))) unsigned int*)l, 16, 0, 0);
}

// ---------------- Kernel B: 64-row reg-panel x 128-col steps ----------------
// B LDS rows = 128 bf16 = 256 B = 16 chunks of 16B. ds_read swizzle:
// byte ^= ((row&7)<<4); global_load_lds writes linearly so the SOURCE
// chunk index carries the same involution (rule #21).
__global__ __launch_bounds__(256) void neg_panel_kernel(const unsigned short* __restrict__ Xbf,
                                                        const float* __restrict__ pos_min,
                                                        float* __restrict__ row_sum,
                                                        float* __restrict__ row_cnt) {
    __shared__ unsigned short Bs[2][BN * DD];  // 2 x 32 KB
    const int tid  = threadIdx.x;
    const int lane = tid & 63;
    const int w    = tid >> 6;      // 0..3 : 32-col band within the 128-col step
    const int l15  = lane & 15, l4 = lane >> 4;
    const int i0   = blockIdx.x * BM;
    const int jb   = blockIdx.y * JC;

    // ---- stage B tile 0: 2048 chunks, 8 per thread
#pragma unroll
    for (int it = 0; it < 8; ++it) {
        int ch  = it * 256 + tid;
        int row = ch >> 4, c4 = ch & 15, srcc = c4 ^ (row & 7);
        async16(Xbf + (((size_t)(jb + row)) << 7) + srcc * 8, &Bs[0][ch * 8]);
    }

    // ---- full 64-row A panel -> registers (held for the whole j-stream)
    short8 areg[4][4];
#pragma unroll
    for (int m = 0; m < 4; ++m) {
        const int row = i0 + m * 16 + l15;
#pragma unroll
        for (int kk = 0; kk < 4; ++kk)
            areg[m][kk] = *(const short8*)(Xbf + (((size_t)row) << 7) + kk * 32 + l4 * 8);
    }

    // per-lane thresholds / class ids for the 16 rows this lane reduces
    float thr[4][4];
    int   i3[4];
#pragma unroll
    for (int m = 0; m < 4; ++m) {
        const int ib = i0 + m * 16 + l4 * 4;
        i3[m] = ib >> 3;  // rows ib..ib+3 share one class (4-aligned quad in 8-block)
#pragma unroll
        for (int r = 0; r < 4; ++r) thr[m][r] = pos_min[ib + r] - MARGIN;
    }
    float s[4][4] = {{0.f}}, c[4][4] = {{0.f}};

    __syncthreads();  // B0 resident (barrier drains vmcnt)

    for (int t = 0; t < JT; ++t) {
        if (t + 1 < JT) {
            const int jb2 = jb + (t + 1) * BN;
#pragma unroll
            for (int it = 0; it < 8; ++it) {
                int ch  = it * 256 + tid;
                int row = ch >> 4, c4 = ch & 15, srcc = c4 ^ (row & 7);
                async16(Xbf + (((size_t)(jb2 + row)) << 7) + srcc * 8,
                        &Bs[(t + 1) & 1][ch * 8]);
            }
        }
        const unsigned short* Bp = Bs[t & 1];

        f32x4 acc[4][2] = {};
#pragma unroll
        for (int kk = 0; kk < DD / 32; ++kk) {
            short8 b[2];
            const int kb = (kk * 32 + l4 * 8) * 2;
#pragma unroll
            for (int n = 0; n < 2; ++n) {
                int rb = w * 32 + n * 16 + l15;
                b[n] = *(const short8*)((const char*)Bp + ((rb * 256 + kb) ^ ((rb & 7) << 4)));
            }
#pragma unroll
            for (int m = 0; m < 4; ++m)
#pragma unroll
                for (int n = 0; n < 2; ++n)
                    acc[m][n] = __builtin_amdgcn_mfma_f32_16x16x32_bf16(areg[m][kk], b[n], acc[m][n], 0, 0, 0);
        }

        // mask-accumulate (C/D layout: col=lane&15, row=(lane>>4)*4+reg)
        const int jt0 = jb + t * BN;
        const int jc0 = jt0 + w * 32 + l15;
        const bool sdiag = (jt0 < i0 + BM) && (i0 < jt0 + BN);
        if (sdiag) {
#pragma unroll
            for (int n = 0; n < 2; ++n) {
                const int j3 = (jc0 + n * 16) >> 3;
#pragma unroll
                for (int m = 0; m < 4; ++m)
#pragma unroll
                    for (int r = 0; r < 4; ++r) {
                        float v = acc[m][n][r];
                        bool k = (v > thr[m][r]) && (i3[m] != j3);
                        s[m][r] += k ? v : 0.f;
                        c[m][r] += k ? 1.f : 0.f;
                    }
            }
        } else {
#pragma unroll
            for (int n = 0; n < 2; ++n)
#pragma unroll
                for (int m = 0; m < 4; ++m)
#pragma unroll
                    for (int r = 0; r < 4; ++r) {
                        float v = acc[m][n][r];
                        bool k = (v > thr[m][r]);
                        s[m][r] += k ? v : 0.f;
                        c[m][r] += k ? 1.f : 0.f;
                    }
        }
        __syncthreads();  // stage t+1 landed; all reads of Bs[t&1] done
    }

    // ---- once per block: reduce across the 16 col-lanes, then atomics.
    // All 4 waves cover the same rows -> 4 atomic pairs per row per block.
#pragma unroll
    for (int m = 0; m < 4; ++m)
#pragma unroll
        for (int r = 0; r < 4; ++r) {
            float sv = s[m][r], cv = c[m][r];
#pragma unroll
            for (int off = 1; off < 16; off <<= 1) {
                sv += __shfl_xor(sv, off);
                cv += __shfl_xor(cv, off);
            }
            if (l15 == 0) {
                int i = i0 + m * 16 + l4 * 4 + r;
                atomicAdd(&row_sum[i], sv);
                atomicAdd(&row_cnt[i], cv);
            }
        }
}

// ---------------- Kernel C: finalize ----------------
__global__ __launch_bounds__(1024) void finalize_kernel(const float* __restrict__ row_sum,
                                                        const float* __restrict__ row_cnt,
                                                        const float* __restrict__ pos_min,
                                                        float* __restrict__ out) {
    __shared__ float red[1024];
    const int tid = threadIdx.x;
    float local = 0.f;
#pragma unroll
    for (int it = 0; it < NN / 1024; ++it) {
        int i = tid + it * 1024;
        float cnt = row_cnt[i];
        if (cnt > 0.f) {
            float nm = row_sum[i] / fmaxf(cnt, 1.0f);
            local += nm - pos_min[i] + MARGIN;
        }
    }
    red[tid] = local;
    __syncthreads();
    for (int st = 512; st > 0; st >>= 1) {
        if (tid < st) red[tid] += red[tid + st];
        __syncthreads();
    }
    if (tid == 0) out[0] = red[0] / (float)NN;
}

extern "C" void kernel_launch(void* const* d_in, const int* in_sizes, int n_in,
                              void* d_out, int out_size, void* d_ws, size_t ws_size,
                              hipStream_t stream) {
    const float* X = (const float*)d_in[0];
    float* pos_min = (float*)d_ws;
    float* row_sum = pos_min + NN;
    float* row_cnt = row_sum + NN;
    unsigned short* Xbf = (unsigned short*)((char*)d_ws + (size_t)3 * NN * 4);

    pos_kernel<<<NN / KK, 64, 0, stream>>>(X, pos_min, row_sum, row_cnt, Xbf);
    dim3 grid(NN / BM, NN / JC);
    neg_panel_kernel<<<grid, 256, 0, stream>>>(Xbf, pos_min, row_sum, row_cnt);
    finalize_kernel<<<1, 1024, 0, stream>>>(row_sum, row_cnt, pos_min, (float*)d_out);
}